// Round 3
// baseline (1350.811 us; speedup 1.0000x reference)
//
#include <hip/hip_runtime.h>

#define K_CODES 4096
#define D 256
#define N_VEC 32768
#define N_ELEM 8388608   // 32*256*32*32
#define BM 64
#define BN 64
#define BK 64
#define KSPLIT 2
#define KT_PER (K_CODES / KSPLIT / BN)  // 32 k-tiles per block
#define WINDOW 1.5e-4f

// ws layout (bytes)
#define WS_LOSS 0                          // float
#define WS_COUNT 8                         // unsigned int
#define WS_IDX 256                         // int[N_VEC]            = 128 KB
#define WS_CAND (256 + N_VEC * 4)          // ull[4][N_VEC]         = 1 MB
#define WS_LIST (WS_CAND + 4 * N_VEC * 8)  // int[N_VEC]            = 128 KB
#define WS_ESQ (WS_LIST + N_VEC * 4)       // float[K_CODES]        = 16 KB
#define WS_ZSQ (WS_ESQ + K_CODES * 4)      // float[N_VEC]          = 128 KB

__device__ __forceinline__ unsigned long long pack_key(float s, int idx) {
  const unsigned u = __float_as_uint(s);
  const unsigned mk = (u & 0x80000000u) ? ~u : (u | 0x80000000u);
  return ((unsigned long long)mk << 12) | (unsigned long long)(unsigned)idx;
}
__device__ __forceinline__ float key_score(unsigned long long k) {
  const unsigned mk = (unsigned)(k >> 12);
  const unsigned u = (mk & 0x80000000u) ? (mk & 0x7fffffffu) : ~mk;
  return __uint_as_float(u);
}

// ---- e_sq: fp32-squared terms, f64 accumulate, f32 round (≈np ±2ulp) -------
__global__ __launch_bounds__(256) void esq_kernel(const float* __restrict__ cb,
                                                  float* __restrict__ esq) {
  const int lane = threadIdx.x & 63;
  const int k = blockIdx.x * 4 + (threadIdx.x >> 6);
  const float* row = cb + (size_t)k * D;
  double s = 0.;
#pragma unroll
  for (int j = 0; j < 4; ++j) {
    const float v = row[lane + 64 * j];
    s += (double)__fmul_rn(v, v);
  }
#pragma unroll
  for (int off = 32; off > 0; off >>= 1) s += __shfl_down(s, off, 64);
  if (lane == 0) esq[k] = (float)s;
}

// ---- z_sq per position: strided reads (coalesced across lanes) -------------
__global__ __launch_bounds__(256) void zsq_kernel(const float* __restrict__ z,
                                                  float* __restrict__ zsq) {
  const int n = blockIdx.x * 256 + threadIdx.x;
  const int b = n >> 10;
  const int hw = n & 1023;
  const float* p = z + ((size_t)b << 18) + hw;
  double a0 = 0., a1 = 0., a2 = 0., a3 = 0.;
  for (int c = 0; c < D; c += 4) {
    const float v0 = p[(size_t)(c + 0) << 10];
    const float v1 = p[(size_t)(c + 1) << 10];
    const float v2 = p[(size_t)(c + 2) << 10];
    const float v3 = p[(size_t)(c + 3) << 10];
    a0 += (double)__fmul_rn(v0, v0);
    a1 += (double)__fmul_rn(v1, v1);
    a2 += (double)__fmul_rn(v2, v2);
    a3 += (double)__fmul_rn(v3, v3);
  }
  zsq[n] = (float)((a0 + a1) + (a2 + a3));
}

// ------------- fused distance + top-2 fine argmin (fp32 tiled GEMM) ---------
__global__ __launch_bounds__(256) void dist_argmin_kernel(
    const float* __restrict__ z, const float* __restrict__ cb,
    const float* __restrict__ esq, unsigned long long* __restrict__ cand) {
  __shared__ float zs[BK][BM + 4];
  __shared__ float cs[BK][BN + 4];
  const int tid = threadIdx.x;
  const int n0 = blockIdx.x * BM;
  const int b = n0 >> 10;
  const int hw0 = n0 & 1023;
  const float* zbase = z + ((size_t)b << 18) + hw0;
  const int tn = tid >> 4;
  const int tk = tid & 15;

  float s1[4], s2[4];
  int i1[4], i2[4];
#pragma unroll
  for (int i = 0; i < 4; ++i) {
    s1[i] = 3.4e38f; s2[i] = 3.4e38f; i1[i] = 0; i2[i] = 0;
  }

  const int kt0 = blockIdx.y * KT_PER;
  for (int kt = 0; kt < KT_PER; ++kt) {
    const int k0 = (kt0 + kt) * BN;
    float acc[4][4];
#pragma unroll
    for (int i = 0; i < 4; ++i)
#pragma unroll
      for (int j = 0; j < 4; ++j) acc[i][j] = 0.f;

    for (int dt = 0; dt < D / BK; ++dt) {
      {
        const int n4 = (tid & 15) * 4;
        const int r0 = tid >> 4;
#pragma unroll
        for (int rr = 0; rr < 4; ++rr) {
          const int d = r0 + rr * 16;
          const float4 v =
              *(const float4*)(zbase + (size_t)(dt * BK + d) * 1024 + n4);
          *(float4*)&zs[d][n4] = v;
        }
      }
      {
        const int c4 = (tid & 15) * 4;
        const int kl0 = tid >> 4;
#pragma unroll
        for (int kk = 0; kk < 4; ++kk) {
          const int kl = kl0 + kk * 16;
          const float4 v =
              *(const float4*)(cb + (size_t)(k0 + kl) * D + dt * BK + c4);
          cs[c4 + 0][kl] = v.x;
          cs[c4 + 1][kl] = v.y;
          cs[c4 + 2][kl] = v.z;
          cs[c4 + 3][kl] = v.w;
        }
      }
      __syncthreads();
#pragma unroll 8
      for (int d = 0; d < BK; ++d) {
        const float4 za = *(const float4*)&zs[d][tn * 4];
        const float4 cv = *(const float4*)&cs[d][tk * 4];
        const float av[4] = {za.x, za.y, za.z, za.w};
        const float bv[4] = {cv.x, cv.y, cv.z, cv.w};
#pragma unroll
        for (int i = 0; i < 4; ++i)
#pragma unroll
          for (int j = 0; j < 4; ++j)
            acc[i][j] = fmaf(av[i], bv[j], acc[i][j]);
      }
      __syncthreads();
    }
#pragma unroll
    for (int j = 0; j < 4; ++j) {
      const int k = k0 + tk * 4 + j;
      const float e = esq[k];
#pragma unroll
      for (int i = 0; i < 4; ++i) {
        const float s = fmaf(-2.f, acc[i][j], e);
        if (s < s1[i]) {
          s2[i] = s1[i]; i2[i] = i1[i]; s1[i] = s; i1[i] = k;
        } else if (s < s2[i]) {
          s2[i] = s; i2[i] = k;
        }
      }
    }
  }

  const int ks = blockIdx.y;
#pragma unroll
  for (int i = 0; i < 4; ++i) {
    float a1 = s1[i], a2 = s2[i];
    int ai1 = i1[i], ai2 = i2[i];
#pragma unroll
    for (int off = 8; off > 0; off >>= 1) {
      float b1 = __shfl_xor(a1, off, 16);
      int bi1 = __shfl_xor(ai1, off, 16);
      float b2 = __shfl_xor(a2, off, 16);
      int bi2 = __shfl_xor(ai2, off, 16);
      if (b1 < a1 || (b1 == a1 && bi1 < ai1)) {
        float t = a1; a1 = b1; b1 = t;
        int ti = ai1; ai1 = bi1; bi1 = ti;
        t = a2; a2 = b2; b2 = t;
        ti = ai2; ai2 = bi2; bi2 = ti;
      }
      if (b1 < a2 || (b1 == a2 && bi1 < ai2)) { a2 = b1; ai2 = bi1; }
    }
    if (tk == 0) {
      const int n = n0 + tn * 4 + i;
      cand[(size_t)(ks * 2 + 0) * N_VEC + n] = pack_key(a1, ai1);
      cand[(size_t)(ks * 2 + 1) * N_VEC + n] = pack_key(a2, ai2);
    }
  }
}

// -- merge k-split top-2; fine winner to idx; near-window positions to list --
__global__ __launch_bounds__(256) void merge_kernel(
    const unsigned long long* __restrict__ cand, int* __restrict__ idx,
    int* __restrict__ list, unsigned int* __restrict__ count) {
  const int n = blockIdx.x * 256 + threadIdx.x;
  const unsigned long long c00 = cand[n];
  const unsigned long long c01 = cand[(size_t)N_VEC + n];
  const unsigned long long c10 = cand[(size_t)2 * N_VEC + n];
  const unsigned long long c11 = cand[(size_t)3 * N_VEC + n];
  const unsigned long long lo1 = min(c00, c01), hi1 = max(c00, c01);
  const unsigned long long lo2 = min(c10, c11), hi2 = max(c10, c11);
  const unsigned long long m1 = min(lo1, lo2);
  const unsigned long long m2 = min(max(lo1, lo2), min(hi1, hi2));
  idx[n] = (int)(m1 & 0xFFFULL);
  if (key_score(m2) - key_score(m1) < WINDOW) {
    const unsigned pos = atomicAdd(count, 1u);
    if (pos < N_VEC) list[pos] = n;
  }
}

// -- rescan flagged positions: emulate np fp32 chain over ALL 4096 codes -----
// d[k] = fl( fl(z_sq - fl(2 * (float)dot64)) + e_sq[k] ), argmin ties->low k
__global__ __launch_bounds__(256) void rescan_kernel(
    const float* __restrict__ z, const float* __restrict__ cb,
    const float* __restrict__ esq, const float* __restrict__ zsq,
    const int* __restrict__ list, const unsigned int* __restrict__ count,
    int* __restrict__ idx) {
  __shared__ float zrow[D];
  __shared__ float dred[256];
  __shared__ int kred[256];
  unsigned int cnt = *count;
  if (cnt > N_VEC) cnt = N_VEC;
  for (unsigned int r = blockIdx.x; r < cnt; r += gridDim.x) {
    const int n = list[r];
    const int b = n >> 10;
    const int hw = n & 1023;
    zrow[threadIdx.x] =
        z[((size_t)b << 18) + ((size_t)threadIdx.x << 10) + hw];
    __syncthreads();
    const float zs = zsq[n];
    float bestd = 3.4e38f;
    int bestk = 0;
    for (int k = threadIdx.x; k < K_CODES; k += 256) {
      const float* row = cb + (size_t)k * D;
      double a0 = 0., a1 = 0., a2 = 0., a3 = 0.;
      for (int c = 0; c < D; c += 4) {
        a0 = fma((double)zrow[c + 0], (double)row[c + 0], a0);
        a1 = fma((double)zrow[c + 1], (double)row[c + 1], a1);
        a2 = fma((double)zrow[c + 2], (double)row[c + 2], a2);
        a3 = fma((double)zrow[c + 3], (double)row[c + 3], a3);
      }
      const float dotf = (float)((a0 + a1) + (a2 + a3));
      const float tmp = __fsub_rn(zs, __fmul_rn(2.0f, dotf));
      const float d = __fadd_rn(tmp, esq[k]);
      if (d < bestd) { bestd = d; bestk = k; }  // ascending k: ties keep low k
    }
    dred[threadIdx.x] = bestd;
    kred[threadIdx.x] = bestk;
    __syncthreads();
    for (int s = 128; s > 0; s >>= 1) {
      if (threadIdx.x < (unsigned)s) {
        const float od = dred[threadIdx.x + s];
        const int ok = kred[threadIdx.x + s];
        if (od < dred[threadIdx.x] ||
            (od == dred[threadIdx.x] && ok < kred[threadIdx.x])) {
          dred[threadIdx.x] = od;
          kred[threadIdx.x] = ok;
        }
      }
      __syncthreads();
    }
    if (threadIdx.x == 0) idx[n] = kred[0];
    __syncthreads();
  }
}

// --------- gather z_q, write z_q_st + indices, accumulate loss sum ----------
__global__ __launch_bounds__(256) void gather_kernel(
    const float* __restrict__ z, const float* __restrict__ cb,
    const int* __restrict__ idxarr, float* __restrict__ out,
    float* __restrict__ loss_acc) {
  const int tid = threadIdx.x;
  const int n0 = blockIdx.x * 64;
  const int hwl = tid & 63;
  const int c0 = tid >> 6;
  const int n = n0 + hwl;
  const int b = n >> 10;
  const int hw = n & 1023;
  const int idx = idxarr[n];
  if (tid < 64) out[(size_t)N_ELEM + 1 + n] = (float)idx;
  const float* crow = cb + (size_t)idx * D;
  const size_t obase = ((size_t)b << 18) + hw;
  float part = 0.f;
#pragma unroll
  for (int c = c0; c < D; c += 4) {
    const float v = crow[c];
    const size_t o = obase + ((size_t)c << 10);
    const float diff = v - z[o];
    out[o] = v;
    part = fmaf(diff, diff, part);
  }
#pragma unroll
  for (int off = 32; off > 0; off >>= 1) part += __shfl_down(part, off, 64);
  __shared__ float red[4];
  if ((tid & 63) == 0) red[tid >> 6] = part;
  __syncthreads();
  if (tid == 0) atomicAdd(loss_acc, red[0] + red[1] + red[2] + red[3]);
}

__global__ void finalize_kernel(const float* __restrict__ loss_acc,
                                float* __restrict__ out) {
  if (threadIdx.x == 0 && blockIdx.x == 0)
    out[N_ELEM] = 1.25f * loss_acc[0] * (1.0f / (float)N_ELEM);
}

extern "C" void kernel_launch(void* const* d_in, const int* in_sizes, int n_in,
                              void* d_out, int out_size, void* d_ws,
                              size_t ws_size, hipStream_t stream) {
  const float* z = (const float*)d_in[0];
  const float* cb = (const float*)d_in[1];
  float* out = (float*)d_out;
  char* ws = (char*)d_ws;
  float* loss_acc = (float*)(ws + WS_LOSS);
  unsigned int* count = (unsigned int*)(ws + WS_COUNT);
  int* idx = (int*)(ws + WS_IDX);
  unsigned long long* cand = (unsigned long long*)(ws + WS_CAND);
  int* list = (int*)(ws + WS_LIST);
  float* esq = (float*)(ws + WS_ESQ);
  float* zsq = (float*)(ws + WS_ZSQ);

  hipMemsetAsync(ws, 0, 256, stream);
  esq_kernel<<<K_CODES / 4, 256, 0, stream>>>(cb, esq);
  zsq_kernel<<<N_VEC / 256, 256, 0, stream>>>(z, zsq);
  dist_argmin_kernel<<<dim3(N_VEC / BM, KSPLIT), 256, 0, stream>>>(z, cb, esq,
                                                                   cand);
  merge_kernel<<<N_VEC / 256, 256, 0, stream>>>(cand, idx, list, count);
  rescan_kernel<<<256, 256, 0, stream>>>(z, cb, esq, zsq, list, count, idx);
  gather_kernel<<<N_VEC / 64, 256, 0, stream>>>(z, cb, idx, out, loss_acc);
  finalize_kernel<<<1, 64, 0, stream>>>(loss_acc, out);
}

// Round 4
// 612.480 us; speedup vs baseline: 2.2055x; 2.2055x over previous
//
#include <hip/hip_runtime.h>

#define K_CODES 4096
#define D 256
#define N_VEC 32768
#define N_ELEM 8388608   // 32*256*32*32
#define WINDOW 2e-4f
#define NSLOT 8

typedef _Float16 f16x8 __attribute__((ext_vector_type(8)));
typedef float f32x4 __attribute__((ext_vector_type(4)));
typedef const __attribute__((address_space(1))) _Float16* gptr_t;
typedef __attribute__((address_space(3))) _Float16* lptr_t;

// ws layout (bytes)
#define WS_LOSS 0
#define WS_COUNT 8
#define WS_IDX 256
#define WS_LIST (WS_IDX + N_VEC * 4)
#define WS_ESQ (WS_LIST + N_VEC * 4)
#define WS_ZSQ (WS_ESQ + K_CODES * 4)
#define WS_CAND (WS_ZSQ + N_VEC * 4)
#define WS_APACK (WS_CAND + NSLOT * N_VEC * 8)          // f16[N_VEC][512]
#define WS_BPACK (WS_APACK + (size_t)N_VEC * 512 * 2)   // f16[K_CODES][512]

__device__ __forceinline__ unsigned long long pack_key(float s, int idx) {
  const unsigned u = __float_as_uint(s);
  const unsigned mk = (u & 0x80000000u) ? ~u : (u | 0x80000000u);
  return ((unsigned long long)mk << 12) | (unsigned long long)(unsigned)idx;
}
__device__ __forceinline__ float key_score(unsigned long long k) {
  const unsigned mk = (unsigned)(k >> 12);
  const unsigned u = (mk & 0x80000000u) ? (mk & 0x7fffffffu) : ~mk;
  return __uint_as_float(u);
}

// ---- e_sq: fp32-squared terms, f64 accumulate, f32 round (frozen: R3) ------
__global__ __launch_bounds__(256) void esq_kernel(const float* __restrict__ cb,
                                                  float* __restrict__ esq) {
  const int lane = threadIdx.x & 63;
  const int k = blockIdx.x * 4 + (threadIdx.x >> 6);
  const float* row = cb + (size_t)k * D;
  double s = 0.;
#pragma unroll
  for (int j = 0; j < 4; ++j) {
    const float v = row[lane + 64 * j];
    s += (double)__fmul_rn(v, v);
  }
#pragma unroll
  for (int off = 32; off > 0; off >>= 1) s += __shfl_down(s, off, 64);
  if (lane == 0) esq[k] = (float)s;
}

// ---- z_sq per position (frozen: R3) ----------------------------------------
__global__ __launch_bounds__(256) void zsq_kernel(const float* __restrict__ z,
                                                  float* __restrict__ zsq) {
  const int n = blockIdx.x * 256 + threadIdx.x;
  const int b = n >> 10;
  const int hw = n & 1023;
  const float* p = z + ((size_t)b << 18) + hw;
  double a0 = 0., a1 = 0., a2 = 0., a3 = 0.;
  for (int c = 0; c < D; c += 4) {
    const float v0 = p[(size_t)(c + 0) << 10];
    const float v1 = p[(size_t)(c + 1) << 10];
    const float v2 = p[(size_t)(c + 2) << 10];
    const float v3 = p[(size_t)(c + 3) << 10];
    a0 += (double)__fmul_rn(v0, v0);
    a1 += (double)__fmul_rn(v1, v1);
    a2 += (double)__fmul_rn(v2, v2);
    a3 += (double)__fmul_rn(v3, v3);
  }
  zsq[n] = (float)((a0 + a1) + (a2 + a3));
}

// ---- pack z -> A_packed[n][512] f16: [z_hi | (z - z_hi)*2048] --------------
__global__ __launch_bounds__(256) void pack_z_kernel(const float* __restrict__ z,
                                                     _Float16* __restrict__ Ap) {
  __shared__ float zs[64][65];
  const int t = threadIdx.x;
  const int n0 = blockIdx.x * 64, c0 = blockIdx.y * 64;
  const int b = n0 >> 10, hw0 = n0 & 1023;
  const float* zb = z + ((size_t)b << 18) + hw0;
#pragma unroll
  for (int p = 0; p < 16; ++p) {
    const int cl = p * 4 + (t >> 6);
    zs[cl][t & 63] = zb[((size_t)(c0 + cl) << 10) + (t & 63)];
  }
  __syncthreads();
  const int nl = t >> 2, q = t & 3;
  f16x8 H0, H1, L0, L1;
#pragma unroll
  for (int j = 0; j < 8; ++j) {
    const float v = zs[q * 16 + j][nl];
    const _Float16 hh = (_Float16)v;
    H0[j] = hh;
    L0[j] = (_Float16)((v - (float)hh) * 2048.f);
    const float v2 = zs[q * 16 + 8 + j][nl];
    const _Float16 h2 = (_Float16)v2;
    H1[j] = h2;
    L1[j] = (_Float16)((v2 - (float)h2) * 2048.f);
  }
  _Float16* o = Ap + (size_t)(n0 + nl) * 512 + c0 + q * 16;
  *(f16x8*)o = H0;
  *((f16x8*)o + 1) = H1;
  *(f16x8*)(o + 256) = L0;
  *((f16x8*)(o + 256) + 1) = L1;
}

// ---- pack cb -> B_packed[k][512] f16: [256*e | (256*e)/2048] ---------------
__global__ __launch_bounds__(256) void pack_cb_kernel(const float* __restrict__ cb,
                                                      _Float16* __restrict__ Bp) {
  const int tg = blockIdx.x * 256 + threadIdx.x;  // 65536 total
  const int k = tg >> 4, q = tg & 15;
  const float* row = cb + (size_t)k * D + q * 16;
  f16x8 H0, H1, L0, L1;
#pragma unroll
  for (int j = 0; j < 8; ++j) {
    const _Float16 h0 = (_Float16)(row[j] * 256.f);
    H0[j] = h0;
    L0[j] = (_Float16)((float)h0 * (1.f / 2048.f));
    const _Float16 h1 = (_Float16)(row[8 + j] * 256.f);
    H1[j] = h1;
    L1[j] = (_Float16)((float)h1 * (1.f / 2048.f));
  }
  _Float16* o = Bp + (size_t)k * 512 + q * 16;
  *(f16x8*)o = H0;
  *((f16x8*)o + 1) = H1;
  *(f16x8*)(o + 256) = L0;
  *((f16x8*)(o + 256) + 1) = L1;
}

// ---- MFMA distance + top-2: 128n x 128codes tile, KSPLIT=2 -----------------
// fine score = esq[k] - acc/128, acc = 256*dot(z,e) via f16 split GEMM
__global__ __launch_bounds__(256) void mfma_dist_kernel(
    const _Float16* __restrict__ Ap, const _Float16* __restrict__ Bp,
    const float* __restrict__ esq, unsigned long long* __restrict__ cand) {
  __shared__ _Float16 As[128 * 64];  // [n][kk] 128B rows, g-groups XOR-swizzled
  __shared__ _Float16 Bs[128 * 64];  // [code][kk] same
  __shared__ float esq_s[128];
  const int tid = threadIdx.x;
  const int lane = tid & 63;
  const int w = tid >> 6;
  const int wn = w & 1, wk = w >> 1;
  const int n0 = blockIdx.x * 128;
  const int quad = lane >> 4;
  const int l16 = lane & 15;

  float s1[4], s2[4];
  int i1[4], i2[4];
#pragma unroll
  for (int i = 0; i < 4; ++i) {
    s1[i] = 3.4e38f; s2[i] = 3.4e38f; i1[i] = 0; i2[i] = 0;
  }

  for (int kt = 0; kt < 16; ++kt) {
    const int k0 = blockIdx.y * 2048 + kt * 128;
    if (tid < 128) esq_s[tid] = esq[k0 + tid];
    f32x4 acc[4][4];
#pragma unroll
    for (int ci = 0; ci < 4; ++ci)
#pragma unroll
      for (int nj = 0; nj < 4; ++nj) acc[ci][nj] = (f32x4)0.f;

    for (int c = 0; c < 8; ++c) {
      // stage: lane-contiguous LDS writes; global g-group XOR'd by row&7
#pragma unroll
      for (int i = 0; i < 4; ++i) {
        const int off = i * 256 + tid;
        const int row = off >> 3;
        const int g = (off & 7) ^ (row & 7);
        const _Float16* gpA = Ap + (size_t)(n0 + row) * 512 + c * 64 + g * 8;
        const _Float16* gpB = Bp + (size_t)(k0 + row) * 512 + c * 64 + g * 8;
        _Float16* lpA = As + (size_t)(i * 256 + w * 64) * 8;
        _Float16* lpB = Bs + (size_t)(i * 256 + w * 64) * 8;
        __builtin_amdgcn_global_load_lds((gptr_t)gpA, (lptr_t)lpA, 16, 0, 0);
        __builtin_amdgcn_global_load_lds((gptr_t)gpB, (lptr_t)lpB, 16, 0, 0);
      }
      __syncthreads();
#pragma unroll
      for (int ks = 0; ks < 2; ++ks) {
        f16x8 a[4], b[4];
#pragma unroll
        for (int ci = 0; ci < 4; ++ci) {
          const int row = wk * 64 + ci * 16 + l16;
          const int g = (ks * 4 + quad) ^ (row & 7);
          a[ci] = *(const f16x8*)(Bs + row * 64 + g * 8);
        }
#pragma unroll
        for (int nj = 0; nj < 4; ++nj) {
          const int row = wn * 64 + nj * 16 + l16;
          const int g = (ks * 4 + quad) ^ (row & 7);
          b[nj] = *(const f16x8*)(As + row * 64 + g * 8);
        }
#pragma unroll
        for (int ci = 0; ci < 4; ++ci)
#pragma unroll
          for (int nj = 0; nj < 4; ++nj)
            acc[ci][nj] = __builtin_amdgcn_mfma_f32_16x16x32_f16(
                a[ci], b[nj], acc[ci][nj], 0, 0, 0);
      }
      __syncthreads();
    }
    // fold 128 codes into running top-2 (codes ascend -> ties keep low idx)
#pragma unroll
    for (int ci = 0; ci < 4; ++ci) {
      const int row0 = wk * 64 + ci * 16 + quad * 4;
      const float4 e4 = *(const float4*)&esq_s[row0];
      const float ev[4] = {e4.x, e4.y, e4.z, e4.w};
#pragma unroll
      for (int r = 0; r < 4; ++r) {
        const int code = k0 + row0 + r;
#pragma unroll
        for (int nj = 0; nj < 4; ++nj) {
          const float s = fmaf(acc[ci][nj][r], -0.0078125f, ev[r]);
          if (s < s1[nj]) {
            s2[nj] = s1[nj]; i2[nj] = i1[nj]; s1[nj] = s; i1[nj] = code;
          } else if (s < s2[nj]) {
            s2[nj] = s; i2[nj] = code;
          }
        }
      }
    }
    __syncthreads();
  }
  // cross-lane merge over the 4 row-quads (lanes l, l^16, l^32, l^48)
#pragma unroll
  for (int nj = 0; nj < 4; ++nj) {
    float a1 = s1[nj], a2 = s2[nj];
    int ai1 = i1[nj], ai2 = i2[nj];
#pragma unroll
    for (int m = 16; m <= 32; m <<= 1) {
      float b1 = __shfl_xor(a1, m, 64);
      int bi1 = __shfl_xor(ai1, m, 64);
      float b2 = __shfl_xor(a2, m, 64);
      int bi2 = __shfl_xor(ai2, m, 64);
      if (b1 < a1 || (b1 == a1 && bi1 < ai1)) {
        float t = a1; a1 = b1; b1 = t;
        int ti = ai1; ai1 = bi1; bi1 = ti;
        t = a2; a2 = b2; b2 = t;
        ti = ai2; ai2 = bi2; bi2 = ti;
      }
      if (b1 < a2 || (b1 == a2 && bi1 < ai2)) { a2 = b1; ai2 = bi1; }
    }
    if (quad == 0) {
      const int n = n0 + wn * 64 + nj * 16 + l16;
      const int slot0 = (blockIdx.y * 2 + wk) * 2;
      cand[(size_t)slot0 * N_VEC + n] = pack_key(a1, ai1);
      cand[(size_t)(slot0 + 1) * N_VEC + n] = pack_key(a2, ai2);
    }
  }
}

// ---- merge 8 candidate slots; flag near-window positions -------------------
__global__ __launch_bounds__(256) void merge_kernel(
    const unsigned long long* __restrict__ cand, int* __restrict__ idx,
    int* __restrict__ list, unsigned int* __restrict__ count) {
  const int n = blockIdx.x * 256 + threadIdx.x;
  unsigned long long m1 = ~0ull, m2 = ~0ull;
#pragma unroll
  for (int s = 0; s < NSLOT; ++s) {
    const unsigned long long c = cand[(size_t)s * N_VEC + n];
    if (c < m1) { m2 = m1; m1 = c; }
    else if (c < m2) { m2 = c; }
  }
  idx[n] = (int)(m1 & 0xFFFULL);
  if (key_score(m2) - key_score(m1) < WINDOW) {
    const unsigned pos = atomicAdd(count, 1u);
    if (pos < N_VEC) list[pos] = n;
  }
}

// ---- rescan flagged positions: np fp32 chain emulation (frozen: R3) --------
__global__ __launch_bounds__(256) void rescan_kernel(
    const float* __restrict__ z, const float* __restrict__ cb,
    const float* __restrict__ esq, const float* __restrict__ zsq,
    const int* __restrict__ list, const unsigned int* __restrict__ count,
    int* __restrict__ idx) {
  __shared__ float zrow[D];
  __shared__ float dred[256];
  __shared__ int kred[256];
  unsigned int cnt = *count;
  if (cnt > N_VEC) cnt = N_VEC;
  for (unsigned int r = blockIdx.x; r < cnt; r += gridDim.x) {
    const int n = list[r];
    const int b = n >> 10;
    const int hw = n & 1023;
    zrow[threadIdx.x] = z[((size_t)b << 18) + ((size_t)threadIdx.x << 10) + hw];
    __syncthreads();
    const float zs = zsq[n];
    float bestd = 3.4e38f;
    int bestk = 0;
    for (int k = threadIdx.x; k < K_CODES; k += 256) {
      const float* row = cb + (size_t)k * D;
      double a0 = 0., a1 = 0., a2 = 0., a3 = 0.;
      for (int c = 0; c < D; c += 4) {
        a0 = fma((double)zrow[c + 0], (double)row[c + 0], a0);
        a1 = fma((double)zrow[c + 1], (double)row[c + 1], a1);
        a2 = fma((double)zrow[c + 2], (double)row[c + 2], a2);
        a3 = fma((double)zrow[c + 3], (double)row[c + 3], a3);
      }
      const float dotf = (float)((a0 + a1) + (a2 + a3));
      const float tmp = __fsub_rn(zs, __fmul_rn(2.0f, dotf));
      const float d = __fadd_rn(tmp, esq[k]);
      if (d < bestd) { bestd = d; bestk = k; }
    }
    dred[threadIdx.x] = bestd;
    kred[threadIdx.x] = bestk;
    __syncthreads();
    for (int s = 128; s > 0; s >>= 1) {
      if (threadIdx.x < (unsigned)s) {
        const float od = dred[threadIdx.x + s];
        const int ok = kred[threadIdx.x + s];
        if (od < dred[threadIdx.x] ||
            (od == dred[threadIdx.x] && ok < kred[threadIdx.x])) {
          dred[threadIdx.x] = od;
          kred[threadIdx.x] = ok;
        }
      }
      __syncthreads();
    }
    if (threadIdx.x == 0) idx[n] = kred[0];
    __syncthreads();
  }
}

// ---- gather z_q, write z_q_st + indices, accumulate loss (frozen: R3) ------
__global__ __launch_bounds__(256) void gather_kernel(
    const float* __restrict__ z, const float* __restrict__ cb,
    const int* __restrict__ idxarr, float* __restrict__ out,
    float* __restrict__ loss_acc) {
  const int tid = threadIdx.x;
  const int n0 = blockIdx.x * 64;
  const int hwl = tid & 63;
  const int c0 = tid >> 6;
  const int n = n0 + hwl;
  const int b = n >> 10;
  const int hw = n & 1023;
  const int idx = idxarr[n];
  if (tid < 64) out[(size_t)N_ELEM + 1 + n] = (float)idx;
  const float* crow = cb + (size_t)idx * D;
  const size_t obase = ((size_t)b << 18) + hw;
  float part = 0.f;
#pragma unroll
  for (int c = c0; c < D; c += 4) {
    const float v = crow[c];
    const size_t o = obase + ((size_t)c << 10);
    const float diff = v - z[o];
    out[o] = v;
    part = fmaf(diff, diff, part);
  }
#pragma unroll
  for (int off = 32; off > 0; off >>= 1) part += __shfl_down(part, off, 64);
  __shared__ float red[4];
  if ((tid & 63) == 0) red[tid >> 6] = part;
  __syncthreads();
  if (tid == 0) atomicAdd(loss_acc, red[0] + red[1] + red[2] + red[3]);
}

__global__ void finalize_kernel(const float* __restrict__ loss_acc,
                                float* __restrict__ out) {
  if (threadIdx.x == 0 && blockIdx.x == 0)
    out[N_ELEM] = 1.25f * loss_acc[0] * (1.0f / (float)N_ELEM);
}

extern "C" void kernel_launch(void* const* d_in, const int* in_sizes, int n_in,
                              void* d_out, int out_size, void* d_ws,
                              size_t ws_size, hipStream_t stream) {
  const float* z = (const float*)d_in[0];
  const float* cb = (const float*)d_in[1];
  float* out = (float*)d_out;
  char* ws = (char*)d_ws;
  float* loss_acc = (float*)(ws + WS_LOSS);
  unsigned int* count = (unsigned int*)(ws + WS_COUNT);
  int* idx = (int*)(ws + WS_IDX);
  int* list = (int*)(ws + WS_LIST);
  float* esq = (float*)(ws + WS_ESQ);
  float* zsq = (float*)(ws + WS_ZSQ);
  unsigned long long* cand = (unsigned long long*)(ws + WS_CAND);
  _Float16* Ap = (_Float16*)(ws + WS_APACK);
  _Float16* Bp = (_Float16*)(ws + WS_BPACK);

  hipMemsetAsync(ws, 0, 256, stream);
  esq_kernel<<<K_CODES / 4, 256, 0, stream>>>(cb, esq);
  zsq_kernel<<<N_VEC / 256, 256, 0, stream>>>(z, zsq);
  pack_z_kernel<<<dim3(N_VEC / 64, 4), 256, 0, stream>>>(z, Ap);
  pack_cb_kernel<<<256, 256, 0, stream>>>(cb, Bp);
  mfma_dist_kernel<<<dim3(N_VEC / 128, 2), 256, 0, stream>>>(Ap, Bp, esq, cand);
  merge_kernel<<<N_VEC / 256, 256, 0, stream>>>(cand, idx, list, count);
  rescan_kernel<<<512, 256, 0, stream>>>(z, cb, esq, zsq, list, count, idx);
  gather_kernel<<<N_VEC / 64, 256, 0, stream>>>(z, cb, idx, out, loss_acc);
  finalize_kernel<<<1, 64, 0, stream>>>(loss_acc, out);
}